// Round 5
// baseline (2495.814 us; speedup 1.0000x reference)
//
#include <hip/hip_runtime.h>

typedef float f32x4 __attribute__((ext_vector_type(4)));

__global__ __launch_bounds__(256) void ToneMapping_kernel(
    const float* __restrict__ x,
    const float* __restrict__ widths,
    const float* __restrict__ heights,
    const float* __restrict__ slopes,
    float* __restrict__ out,
    long long n4, long long n)
{
    // Fold the spline into per-bin rational quadratics y = P_i(xf)/Q_i(xf).
    // ALL parameters are individual named scalars (no arrays!) so the compiler
    // cannot PromoteAlloca them to LDS (R4 pathology: 20KB LDS + 1.3e7 bank
    // conflicts). Selection is a 4-deep v_cndmask cascade per coefficient.
    float c = 0.0f;
    float e0, e1, e2, e3;

#define MKBIN(I, SAVE_EDGE)                                              \
    float p2_##I, p1_##I, p0_##I, q2_##I, q1_##I, q0_##I;                \
    {                                                                    \
        float w  = widths[I];                                            \
        float xl = c;                     /* widths_cumsum[I] */         \
        c = c + w;                        /* bin_edges[I], f32 order */  \
        SAVE_EDGE;                                                       \
        float iw = 1.0f / (w + 1e-8f);                                   \
        float yl = heights[I], yh = heights[I + 1];                      \
        float dy = yh - yl;                                              \
        float sl = slopes[I], sh = slopes[I + 1];                        \
        float ss = sl + sh;                                              \
        float a2 = (sl - 2.0f) * iw * iw;                                \
        float a1 = 2.0f * iw;                                            \
        float b2 = ss * iw * iw;                                         \
        float b1 = (2.0f * ss - 4.0f) * iw;                              \
        float cc2 = fmaf(dy, a2, yl * b2);                               \
        float cc1 = fmaf(dy, a1, yl * b1);                               \
        float cc0 = 2.0f * yl;                                           \
        p2_##I = cc2;                                                    \
        p1_##I = cc1 - 2.0f * cc2 * xl;                                  \
        p0_##I = fmaf(fmaf(cc2, xl, -cc1), xl, cc0);                     \
        q2_##I = b2;                                                     \
        q1_##I = b1 - 2.0f * b2 * xl;                                    \
        q0_##I = fmaf(fmaf(b2, xl, -b1), xl, 2.0f);                      \
    }

    MKBIN(0, e0 = c)
    MKBIN(1, e1 = c)
    MKBIN(2, e2 = c)
    MKBIN(3, e3 = c)
    MKBIN(4, )
#undef MKBIN

    const f32x4* __restrict__ x4 = (const f32x4*)x;
    f32x4* __restrict__ o4 = (f32x4*)out;

    auto eval1 = [&](float xin) -> float {
        float xf = fminf(fmaxf(xin, 0.0f), 1.0f);
        bool g0 = e0 < xf, g1 = e1 < xf, g2 = e2 < xf, g3 = e3 < xf;
        // searchsorted 'left' clipped == 4-deep select cascade (scalars only)
#define SEL(A) (g3 ? A##_4 : (g2 ? A##_3 : (g1 ? A##_2 : (g0 ? A##_1 : A##_0))))
        float p2 = SEL(p2), p1 = SEL(p1), p0 = SEL(p0);
        float q2 = SEL(q2), q1 = SEL(q1), q0 = SEL(q0);
#undef SEL
        float Pv = fmaf(xf, fmaf(xf, p2, p1), p0);   // Horner
        float Qv = fmaf(xf, fmaf(xf, q2, q1), q0);
        return Pv * __builtin_amdgcn_rcpf(Qv);
    };

    long long tid    = (long long)blockIdx.x * blockDim.x + threadIdx.x;
    long long stride = (long long)gridDim.x * blockDim.x;

    for (long long i = tid; i < n4; i += stride) {
        f32x4 v = x4[i];
        f32x4 r;
        r.x = eval1(v.x);
        r.y = eval1(v.y);
        r.z = eval1(v.z);
        r.w = eval1(v.w);
        o4[i] = r;
    }

    // Scalar tail (n % 4 != 0) — not hit for this shape.
    long long ts = n4 * 4;
    for (long long j = ts + tid; j < n; j += stride)
        out[j] = eval1(x[j]);
}

extern "C" void kernel_launch(void* const* d_in, const int* in_sizes, int n_in,
                              void* d_out, int out_size, void* d_ws, size_t ws_size,
                              hipStream_t stream) {
    const float* x       = (const float*)d_in[0];
    const float* widths  = (const float*)d_in[1];
    const float* heights = (const float*)d_in[2];
    const float* slopes  = (const float*)d_in[3];
    float* out = (float*)d_out;

    long long n  = (long long)in_sizes[0];
    long long n4 = n / 4;

    const int block = 256;
    long long want = (n4 + block - 1) / block;
    int grid = (int)(want < 2048 ? (want > 0 ? want : 1) : 2048);

    ToneMapping_kernel<<<grid, block, 0, stream>>>(x, widths, heights, slopes, out, n4, n);
}

// Round 6
// 80.137 us; speedup vs baseline: 31.1445x; 31.1445x over previous
//
#include <hip/hip_runtime.h>

typedef float f32x4 __attribute__((ext_vector_type(4)));

__global__ __launch_bounds__(256) void ToneMapping_kernel(
    const float* __restrict__ x,
    const float* __restrict__ widths,
    const float* __restrict__ heights,
    const float* __restrict__ slopes,
    float* __restrict__ out,
    long long n4, long long n)
{
    // Per-bin spline folded into rational quadratic in xf: y = P_i(xf)/Q_i(xf).
    // Params live in LDS (NOT registers — R4/R5 showed the compiler demotes
    // per-thread tables to LDS-with-conflicts or scratch). Packed so the loop
    // does 1 ds_read_b128 + 1 ds_read_b64 per element (R1 did 11 ds_read_b32
    // -> LDS pipe was the binding resource: 8160 vs 6400 cyc/round).
    __shared__ float4 s_pA[5];   // {P2, P1, P0, Q2}
    __shared__ float2 s_pB[5];   // {Q1, Q0}
    __shared__ float  s_edge[4];

    if (threadIdx.x == 0) {
        float c = 0.0f;
        for (int i = 0; i < 5; ++i) {
            float w  = widths[i];
            float xl = c;                    // widths_cumsum[i]
            c = c + w;                       // bin_edges[i], f32 cumsum order
            if (i < 4) s_edge[i] = c;
            float iw = 1.0f / (w + 1e-8f);
            float yl = heights[i], dy = heights[i + 1] - yl;
            float sl = slopes[i],  ss = sl + slopes[i + 1];
            // in u = xf - xl:  num = a2 u^2 + a1 u ; den = b2 u^2 + b1 u + 2
            float a2 = (sl - 2.0f) * iw * iw;
            float a1 = 2.0f * iw;
            float b2 = ss * iw * iw;
            float b1 = (2.0f * ss - 4.0f) * iw;
            // y = (yl*den + dy*num)/den ; expand u -> xf polynomials
            float cc2 = fmaf(dy, a2, yl * b2);
            float cc1 = fmaf(dy, a1, yl * b1);
            float cc0 = 2.0f * yl;
            float P2 = cc2;
            float P1 = cc1 - 2.0f * cc2 * xl;
            float P0 = fmaf(fmaf(cc2, xl, -cc1), xl, cc0);
            float Q2 = b2;
            float Q1 = b1 - 2.0f * b2 * xl;
            float Q0 = fmaf(fmaf(b2, xl, -b1), xl, 2.0f);
            s_pA[i] = make_float4(P2, P1, P0, Q2);
            s_pB[i] = make_float2(Q1, Q0);
        }
    }
    __syncthreads();

    // Edges in registers: removes 4 ds_reads/elem vs R1.
    float e0 = s_edge[0], e1 = s_edge[1], e2 = s_edge[2], e3 = s_edge[3];

    const f32x4* __restrict__ x4 = (const f32x4*)x;
    f32x4* __restrict__ o4 = (f32x4*)out;

    long long tid    = (long long)blockIdx.x * blockDim.x + threadIdx.x;
    long long stride = (long long)gridDim.x * blockDim.x;

    // Same loop structure as R1 (the only config that hit 79.8us): one float4
    // per thread per grid-stride pass, no manual unroll, no nt hints.
    for (long long i = tid; i < n4; i += stride) {
        f32x4 v = x4[i];
        f32x4 r;
        #pragma unroll
        for (int k = 0; k < 4; ++k) {
            float xf = fminf(fmaxf(v[k], 0.0f), 1.0f);
            // searchsorted(edges, xf, 'left') clipped == count(edges < xf)
            int idx = (int)(e0 < xf) + (int)(e1 < xf) + (int)(e2 < xf) + (int)(e3 < xf);
            float4 pA = s_pA[idx];   // ds_read_b128, banks idx*6.. disjoint
            float2 pB = s_pB[idx];   // ds_read_b64
            float Pv = fmaf(xf, fmaf(xf, pA.x, pA.y), pA.z);
            float Qv = fmaf(xf, fmaf(xf, pA.w, pB.x), pB.y);
            r[k] = Pv * __builtin_amdgcn_rcpf(Qv);
        }
        o4[i] = r;
    }

    // Scalar tail (n % 4 != 0) — not hit for this shape.
    long long ts = n4 * 4;
    for (long long j = ts + tid; j < n; j += stride) {
        float xf = fminf(fmaxf(x[j], 0.0f), 1.0f);
        int idx = (int)(e0 < xf) + (int)(e1 < xf) + (int)(e2 < xf) + (int)(e3 < xf);
        float4 pA = s_pA[idx];
        float2 pB = s_pB[idx];
        float Pv = fmaf(xf, fmaf(xf, pA.x, pA.y), pA.z);
        float Qv = fmaf(xf, fmaf(xf, pA.w, pB.x), pB.y);
        out[j] = Pv * __builtin_amdgcn_rcpf(Qv);
    }
}

extern "C" void kernel_launch(void* const* d_in, const int* in_sizes, int n_in,
                              void* d_out, int out_size, void* d_ws, size_t ws_size,
                              hipStream_t stream) {
    const float* x       = (const float*)d_in[0];
    const float* widths  = (const float*)d_in[1];
    const float* heights = (const float*)d_in[2];
    const float* slopes  = (const float*)d_in[3];
    float* out = (float*)d_out;

    long long n  = (long long)in_sizes[0];
    long long n4 = n / 4;

    const int block = 256;
    long long want = (n4 + block - 1) / block;
    int grid = (int)(want < 2048 ? (want > 0 ? want : 1) : 2048);

    ToneMapping_kernel<<<grid, block, 0, stream>>>(x, widths, heights, slopes, out, n4, n);
}

// Round 7
// 66.075 us; speedup vs baseline: 37.7726x; 1.2128x over previous
//
#include <hip/hip_runtime.h>

typedef float f32x4 __attribute__((ext_vector_type(4)));

__global__ __launch_bounds__(256) void ToneMapping_kernel(
    const float* __restrict__ x,
    const float* __restrict__ widths,
    const float* __restrict__ heights,
    const float* __restrict__ slopes,
    float* __restrict__ out,
    long long n4, long long n)
{
    // Per-bin spline folded into rational quadratic in xf: y = P_i(xf)/Q_i(xf).
    // Params in LDS (R4/R5: per-thread tables get demoted to LDS-with-conflicts
    // or scratch). 1 ds_read_b128 + 1 ds_read_b64 per element.
    //
    // R7 single change vs R6: NON-TEMPORAL STORES (plain loads). Output is
    // write-once/never-read; no-allocate on stores leaves the full 256MB L3
    // for the 201MB input -> input becomes L3-resident across graph replays.
    __shared__ float4 s_pA[5];   // {P2, P1, P0, Q2}
    __shared__ float2 s_pB[5];   // {Q1, Q0}
    __shared__ float  s_edge[4];

    if (threadIdx.x == 0) {
        float c = 0.0f;
        for (int i = 0; i < 5; ++i) {
            float w  = widths[i];
            float xl = c;                    // widths_cumsum[i]
            c = c + w;                       // bin_edges[i], f32 cumsum order
            if (i < 4) s_edge[i] = c;
            float iw = 1.0f / (w + 1e-8f);
            float yl = heights[i], dy = heights[i + 1] - yl;
            float sl = slopes[i],  ss = sl + slopes[i + 1];
            float a2 = (sl - 2.0f) * iw * iw;
            float a1 = 2.0f * iw;
            float b2 = ss * iw * iw;
            float b1 = (2.0f * ss - 4.0f) * iw;
            float cc2 = fmaf(dy, a2, yl * b2);
            float cc1 = fmaf(dy, a1, yl * b1);
            float cc0 = 2.0f * yl;
            float P2 = cc2;
            float P1 = cc1 - 2.0f * cc2 * xl;
            float P0 = fmaf(fmaf(cc2, xl, -cc1), xl, cc0);
            float Q2 = b2;
            float Q1 = b1 - 2.0f * b2 * xl;
            float Q0 = fmaf(fmaf(b2, xl, -b1), xl, 2.0f);
            s_pA[i] = make_float4(P2, P1, P0, Q2);
            s_pB[i] = make_float2(Q1, Q0);
        }
    }
    __syncthreads();

    float e0 = s_edge[0], e1 = s_edge[1], e2 = s_edge[2], e3 = s_edge[3];

    const f32x4* __restrict__ x4 = (const f32x4*)x;
    f32x4* __restrict__ o4 = (f32x4*)out;

    long long tid    = (long long)blockIdx.x * blockDim.x + threadIdx.x;
    long long stride = (long long)gridDim.x * blockDim.x;

    for (long long i = tid; i < n4; i += stride) {
        f32x4 v = x4[i];                       // plain load: DO cache in L3
        f32x4 r;
        #pragma unroll
        for (int k = 0; k < 4; ++k) {
            float xf = fminf(fmaxf(v[k], 0.0f), 1.0f);
            int idx = (int)(e0 < xf) + (int)(e1 < xf) + (int)(e2 < xf) + (int)(e3 < xf);
            float4 pA = s_pA[idx];   // ds_read_b128
            float2 pB = s_pB[idx];   // ds_read_b64
            float Pv = fmaf(xf, fmaf(xf, pA.x, pA.y), pA.z);
            float Qv = fmaf(xf, fmaf(xf, pA.w, pB.x), pB.y);
            r[k] = Pv * __builtin_amdgcn_rcpf(Qv);
        }
        __builtin_nontemporal_store(r, o4 + i);  // no-allocate: keep L3 for input
    }

    // Scalar tail (n % 4 != 0) — not hit for this shape.
    long long ts = n4 * 4;
    for (long long j = ts + tid; j < n; j += stride) {
        float xf = fminf(fmaxf(x[j], 0.0f), 1.0f);
        int idx = (int)(e0 < xf) + (int)(e1 < xf) + (int)(e2 < xf) + (int)(e3 < xf);
        float4 pA = s_pA[idx];
        float2 pB = s_pB[idx];
        float Pv = fmaf(xf, fmaf(xf, pA.x, pA.y), pA.z);
        float Qv = fmaf(xf, fmaf(xf, pA.w, pB.x), pB.y);
        __builtin_nontemporal_store(Pv * __builtin_amdgcn_rcpf(Qv), out + j);
    }
}

extern "C" void kernel_launch(void* const* d_in, const int* in_sizes, int n_in,
                              void* d_out, int out_size, void* d_ws, size_t ws_size,
                              hipStream_t stream) {
    const float* x       = (const float*)d_in[0];
    const float* widths  = (const float*)d_in[1];
    const float* heights = (const float*)d_in[2];
    const float* slopes  = (const float*)d_in[3];
    float* out = (float*)d_out;

    long long n  = (long long)in_sizes[0];
    long long n4 = n / 4;

    const int block = 256;
    long long want = (n4 + block - 1) / block;
    int grid = (int)(want < 2048 ? (want > 0 ? want : 1) : 2048);

    ToneMapping_kernel<<<grid, block, 0, stream>>>(x, widths, heights, slopes, out, n4, n);
}

// Round 8
// 65.137 us; speedup vs baseline: 38.3163x; 1.0144x over previous
//
#include <hip/hip_runtime.h>

typedef float f32x4 __attribute__((ext_vector_type(4)));

__global__ __launch_bounds__(256) void ToneMapping_kernel(
    const float* __restrict__ x,
    const float* __restrict__ widths,
    const float* __restrict__ heights,
    const float* __restrict__ slopes,
    float* __restrict__ out,
    long long n4, long long n)
{
    // R7 + one change: 2x block-contiguous unroll (two loads in flight/wave,
    // wave footprint stays 2KB-contiguous). Params in LDS; nt-store on output
    // (keeps 256MB L3 free for the 201MB input); plain loads.
    __shared__ float4 s_pA[5];   // {P2, P1, P0, Q2}
    __shared__ float2 s_pB[5];   // {Q1, Q0}
    __shared__ float  s_edge[4];

    if (threadIdx.x == 0) {
        float c = 0.0f;
        for (int i = 0; i < 5; ++i) {
            float w  = widths[i];
            float xl = c;                    // widths_cumsum[i]
            c = c + w;                       // bin_edges[i], f32 cumsum order
            if (i < 4) s_edge[i] = c;
            float iw = 1.0f / (w + 1e-8f);
            float yl = heights[i], dy = heights[i + 1] - yl;
            float sl = slopes[i],  ss = sl + slopes[i + 1];
            float a2 = (sl - 2.0f) * iw * iw;
            float a1 = 2.0f * iw;
            float b2 = ss * iw * iw;
            float b1 = (2.0f * ss - 4.0f) * iw;
            float cc2 = fmaf(dy, a2, yl * b2);
            float cc1 = fmaf(dy, a1, yl * b1);
            float cc0 = 2.0f * yl;
            s_pA[i] = make_float4(cc2,
                                  cc1 - 2.0f * cc2 * xl,
                                  fmaf(fmaf(cc2, xl, -cc1), xl, cc0),
                                  b2);
            s_pB[i] = make_float2(b1 - 2.0f * b2 * xl,
                                  fmaf(fmaf(b2, xl, -b1), xl, 2.0f));
        }
    }
    __syncthreads();

    float e0 = s_edge[0], e1 = s_edge[1], e2 = s_edge[2], e3 = s_edge[3];

    const f32x4* __restrict__ x4 = (const f32x4*)x;
    f32x4* __restrict__ o4 = (f32x4*)out;

    auto evalv = [&](f32x4 v) -> f32x4 {
        f32x4 r;
        #pragma unroll
        for (int k = 0; k < 4; ++k) {
            float xf = fminf(fmaxf(v[k], 0.0f), 1.0f);
            int idx = (int)(e0 < xf) + (int)(e1 < xf) + (int)(e2 < xf) + (int)(e3 < xf);
            float4 pA = s_pA[idx];   // ds_read_b128
            float2 pB = s_pB[idx];   // ds_read_b64
            float Pv = fmaf(xf, fmaf(xf, pA.x, pA.y), pA.z);
            float Qv = fmaf(xf, fmaf(xf, pA.w, pB.x), pB.y);
            r[k] = Pv * __builtin_amdgcn_rcpf(Qv);
        }
        return r;
    };

    const long long bd    = blockDim.x;                  // 256
    const long long nthr  = (long long)gridDim.x * bd;
    const long long chunk = 2 * nthr;

    long long full_passes = n4 / chunk;
    long long main_end    = full_passes * chunk;

    for (long long p = 0; p < full_passes; ++p) {
        long long base = p * chunk + (long long)blockIdx.x * (2 * bd) + threadIdx.x;
        f32x4 v0 = x4[base];          // two coalesced loads in flight
        f32x4 v1 = x4[base + bd];
        f32x4 r0 = evalv(v0);
        f32x4 r1 = evalv(v1);
        __builtin_nontemporal_store(r0, o4 + base);
        __builtin_nontemporal_store(r1, o4 + base + bd);
    }

    // Tail float4s — grid-stride.
    for (long long i = main_end + (long long)blockIdx.x * bd + threadIdx.x;
         i < n4; i += nthr) {
        __builtin_nontemporal_store(evalv(x4[i]), o4 + i);
    }

    // Scalar tail (n % 4 != 0) — not hit for this shape.
    long long ts = n4 * 4;
    for (long long j = ts + (long long)blockIdx.x * bd + threadIdx.x; j < n; j += nthr) {
        float xf = fminf(fmaxf(x[j], 0.0f), 1.0f);
        int idx = (int)(e0 < xf) + (int)(e1 < xf) + (int)(e2 < xf) + (int)(e3 < xf);
        float4 pA = s_pA[idx];
        float2 pB = s_pB[idx];
        float Pv = fmaf(xf, fmaf(xf, pA.x, pA.y), pA.z);
        float Qv = fmaf(xf, fmaf(xf, pA.w, pB.x), pB.y);
        __builtin_nontemporal_store(Pv * __builtin_amdgcn_rcpf(Qv), out + j);
    }
}

extern "C" void kernel_launch(void* const* d_in, const int* in_sizes, int n_in,
                              void* d_out, int out_size, void* d_ws, size_t ws_size,
                              hipStream_t stream) {
    const float* x       = (const float*)d_in[0];
    const float* widths  = (const float*)d_in[1];
    const float* heights = (const float*)d_in[2];
    const float* slopes  = (const float*)d_in[3];
    float* out = (float*)d_out;

    long long n  = (long long)in_sizes[0];
    long long n4 = n / 4;

    const int block = 256;
    long long want = (n4 / 2 + block - 1) / block;  // 2 float4s per thread per pass
    int grid = (int)(want < 2048 ? (want > 0 ? want : 1) : 2048);

    ToneMapping_kernel<<<grid, block, 0, stream>>>(x, widths, heights, slopes, out, n4, n);
}